// Round 3
// baseline (835.303 us; speedup 1.0000x reference)
//
#include <hip/hip_runtime.h>
#include <math.h>

// Problem constants (from reference)
#define NN 20000      // nodes
#define EE 640000     // edges
#define HH 2          // heads
#define DD 64         // dim
#define LL 4          // layers
#define HD 128        // H*D
#define BT 16         // edge batch size in fused_aggregate

// ---------------- CSR build ----------------

__global__ void hist_kernel(const int* __restrict__ dst, int* __restrict__ deg) {
    int e = blockIdx.x * 256 + threadIdx.x;
    if (e < EE) atomicAdd(&deg[dst[e]], 1);
}

// single-block exclusive scan, 1024 threads, wave-shuffle based
__global__ void scan_kernel(const int* __restrict__ deg, int* __restrict__ offsets, int n) {
    __shared__ int wsum[16];
    __shared__ int carry;
    int tid = threadIdx.x, wid = tid >> 6, lane = tid & 63;
    if (tid == 0) carry = 0;
    __syncthreads();
    for (int base = 0; base < n; base += 1024) {
        int i = base + tid;
        int v = (i < n) ? deg[i] : 0;
        int x = v;
#pragma unroll
        for (int off = 1; off < 64; off <<= 1) {
            int t = __shfl_up(x, off);
            if (lane >= off) x += t;
        }
        if (lane == 63) wsum[wid] = x;
        __syncthreads();
        if (wid == 0) {
            int wv = (lane < 16) ? wsum[lane] : 0;
#pragma unroll
            for (int off = 1; off < 16; off <<= 1) {
                int t = __shfl_up(wv, off);
                if (lane >= off) wv += t;
            }
            if (lane < 16) wsum[lane] = wv;   // inclusive wave sums
        }
        __syncthreads();
        int prefix = carry + (wid > 0 ? wsum[wid - 1] : 0);
        if (i < n) offsets[i] = prefix + x - v;   // exclusive
        __syncthreads();
        if (tid == 0) carry += wsum[15];
        __syncthreads();
    }
    if (threadIdx.x == 0) offsets[n] = carry;
}

__global__ void scatter_kernel(const int* __restrict__ src, const int* __restrict__ dst,
                               const int* __restrict__ offsets, int* __restrict__ cursor,
                               int* __restrict__ csr_src) {
    int e = blockIdx.x * 256 + threadIdx.x;
    if (e >= EE) return;
    int d = dst[e];
    int pos = offsets[d] + atomicAdd(&cursor[d], 1);
    csr_src[pos] = src[e];
}

// ---------------- per-layer kernels ----------------

// xl = x@Wl + bl ; xr = x@Wr + br  ([N,64] x [64,128])
__global__ void gemm_lr(const float* __restrict__ x,
                        const float* __restrict__ Wl, const float* __restrict__ bl,
                        const float* __restrict__ Wr, const float* __restrict__ br,
                        float* __restrict__ xl, float* __restrict__ xr) {
    __shared__ float xs[16][DD];
    int row0 = blockIdx.x * 16;
    for (int t = threadIdx.x; t < 16 * DD; t += 128) {
        xs[t >> 6][t & 63] = x[row0 * DD + t];
    }
    __syncthreads();
    int j = threadIdx.x;
    float accl[16], accr[16];
    float blv = bl[j], brv = br[j];
#pragma unroll
    for (int r = 0; r < 16; ++r) { accl[r] = blv; accr[r] = brv; }
    for (int k = 0; k < DD; ++k) {
        float wl = Wl[k * HD + j];
        float wr = Wr[k * HD + j];
#pragma unroll
        for (int r = 0; r < 16; ++r) {
            float xv = xs[r][k];
            accl[r] += xv * wl;
            accr[r] += xv * wr;
        }
    }
#pragma unroll
    for (int r = 0; r < 16; ++r) {
        xl[(row0 + r) * HD + j] = accl[r];
        xr[(row0 + r) * HD + j] = accr[r];
    }
}

// Fused GATv2 edge phase with batched LDS-transpose reduction.
// One block per dst node; wave h = head h; lane = feature dim in passes A/B,
// (edge, quarter) in the reduce phase.
__global__ void fused_aggregate(const float* __restrict__ xl, const float* __restrict__ xr,
                                const float* __restrict__ att, const int* __restrict__ offsets,
                                const int* __restrict__ csr_src, const float* __restrict__ bias,
                                float* __restrict__ xout) {
    __shared__ float pbuf[HH][BT][DD + 1];   // att*leaky partials
    __shared__ float xbuf[HH][BT][DD + 1];   // raw gathered xl rows
    __shared__ float hacc[HH][DD];
    int node = blockIdx.x;
    int h = threadIdx.x >> 6;
    int lane = threadIdx.x & 63;
    int e16 = lane & 15;     // edge slot in reduce phase
    int q = lane >> 4;       // quarter-row in reduce phase
    int start = offsets[node];
    int deg = offsets[node + 1] - start;

    float xrv = xr[(long)node * HD + h * 64 + lane];
    float attv = att[h * 64 + lane];

    float m = -INFINITY;   // running max
    float ssum = 0.f;      // running softmax denom
    float acc = 0.f;       // running weighted message (lane = feature)

    for (int base = 0; base < deg; base += BT) {
        int cnt = min(BT, deg - base);
        int sidx = 0;
        if (lane < cnt) sidx = csr_src[start + base + lane];
        __syncthreads();   // previous batch's LDS reads complete before overwrite

        // Pass A: gather xl[src] once per edge; stage partials + raw row in LDS
        int s0 = __shfl(sidx, 0);
        float xlv = xl[(long)s0 * HD + h * 64 + lane];
        for (int j = 0; j < cnt; ++j) {
            float nxt = 0.f;
            if (j + 1 < cnt) {    // wave-uniform; prefetch next edge's gather
                int s1 = __shfl(sidx, j + 1);
                nxt = xl[(long)s1 * HD + h * 64 + lane];
            }
            float v = xlv + xrv;
            v = fmaxf(v, 0.f) + 0.2f * fminf(v, 0.f);   // leaky_relu(0.2)
            pbuf[h][j][lane] = v * attv;
            xbuf[h][j][lane] = xlv;
            xlv = nxt;
        }
        __syncthreads();

        // Reduce: 4 lanes per edge sum quarter-rows (stride-1, conflict-free)
        float s = 0.f;
        const float* row = &pbuf[h][e16][q * 16];
#pragma unroll
        for (int k = 0; k < 16; ++k) s += row[k];
        s += __shfl_xor(s, 16);
        s += __shfl_xor(s, 32);
        float logit = (e16 < cnt) ? s : -INFINITY;

        // batch max + online softmax update (lane-parallel exp)
        float bm = logit;
#pragma unroll
        for (int off = 8; off >= 1; off >>= 1) bm = fmaxf(bm, __shfl_xor(bm, off));
        float mn = fmaxf(m, bm);
        float c = __expf(m - mn);          // exp(-inf)=0 handles first batch
        float w = __expf(logit - mn);      // logit=-inf for invalid slots -> 0
        float ws = w;
#pragma unroll
        for (int off = 8; off >= 1; off >>= 1) ws += __shfl_xor(ws, off);
        ssum = ssum * c + ws;
        acc *= c;
        m = mn;

        // Pass B: weighted message accumulation from LDS (no second gather)
        for (int j = 0; j < cnt; ++j) {
            float wj = __shfl(w, j);
            acc = fmaf(wj, xbuf[h][j][lane], acc);
        }
    }

    float r = acc / (ssum + 1e-16f);      // deg==0 -> 0

    hacc[h][lane] = r;
    __syncthreads();
    if (threadIdx.x < 64) {
        float o = 0.5f * (hacc[0][lane] + hacc[1][lane]) + bias[lane];
        o = o > 0.f ? o : 0.01f * o;      // leaky_relu(0.01)
        xout[node * DD + lane] = o;
    }
}

// out = leaky_relu(x @ Wo + bo, 0.01); 16 rows/block, 64 threads
__global__ void final_gemm(const float* __restrict__ x, const float* __restrict__ Wo,
                           const float* __restrict__ bo, float* __restrict__ out) {
    __shared__ float xs[16][DD];
    int row0 = blockIdx.x * 16;
    for (int t = threadIdx.x; t < 16 * DD; t += 64) {
        xs[t >> 6][t & 63] = x[row0 * DD + t];
    }
    __syncthreads();
    int j = threadIdx.x;
    float acc[16];
    float bv = bo[j];
#pragma unroll
    for (int r = 0; r < 16; ++r) acc[r] = bv;
    for (int k = 0; k < DD; ++k) {
        float w = Wo[k * DD + j];
#pragma unroll
        for (int r = 0; r < 16; ++r) acc[r] += xs[r][k] * w;
    }
#pragma unroll
    for (int r = 0; r < 16; ++r) {
        float v = acc[r];
        v = v > 0.f ? v : 0.01f * v;
        out[(row0 + r) * DD + j] = v;
    }
}

extern "C" void kernel_launch(void* const* d_in, const int* in_sizes, int n_in,
                              void* d_out, int out_size, void* d_ws, size_t ws_size,
                              hipStream_t stream) {
    const int* edge_index = (const int*)d_in[0];
    const int* src = edge_index;
    const int* dst = edge_index + EE;
    // d_in[1] = edge_weight, unused
    const float* pert = (const float*)d_in[2];
    const float* Wl = (const float*)d_in[3];
    const float* bl = (const float*)d_in[4];
    const float* Wr = (const float*)d_in[5];
    const float* br = (const float*)d_in[6];
    const float* att = (const float*)d_in[7];
    const float* bias = (const float*)d_in[8];
    const float* Wo = (const float*)d_in[9];
    const float* bo = (const float*)d_in[10];
    float* out = (float*)d_out;

    // workspace carve-up
    char* w = (char*)d_ws;
    float* xl = (float*)w;            w += (size_t)NN * HD * 4;
    float* xr = (float*)w;            w += (size_t)NN * HD * 4;
    float* xb0 = (float*)w;           w += (size_t)NN * DD * 4;
    float* xb1 = (float*)w;           w += (size_t)NN * DD * 4;
    int* deg = (int*)w;               w += (size_t)NN * 4;
    int* offsets = (int*)w;           w += (size_t)(NN + 1) * 4 + 4; // keep alignment
    int* cursor = (int*)w;            w += (size_t)NN * 4;
    int* csr_src = (int*)w;           w += (size_t)EE * 4;

    // CSR build (dst is layer-invariant; built once per launch)
    hipMemsetAsync(deg, 0, (size_t)NN * 4, stream);
    hipMemsetAsync(cursor, 0, (size_t)NN * 4, stream);
    hist_kernel<<<(EE + 255) / 256, 256, 0, stream>>>(dst, deg);
    scan_kernel<<<1, 1024, 0, stream>>>(deg, offsets, NN);
    scatter_kernel<<<(EE + 255) / 256, 256, 0, stream>>>(src, dst, offsets, cursor, csr_src);

    const float* xin = pert;
    float* bufs[2] = {xb0, xb1};
    for (int l = 0; l < LL; ++l) {
        gemm_lr<<<NN / 16, 128, 0, stream>>>(xin, Wl + (size_t)l * DD * HD, bl + (size_t)l * HD,
                                             Wr + (size_t)l * DD * HD, br + (size_t)l * HD, xl, xr);
        fused_aggregate<<<NN, 128, 0, stream>>>(xl, xr, att + (size_t)l * HD, offsets,
                                                csr_src, bias + (size_t)l * DD, bufs[l & 1]);
        xin = bufs[l & 1];
    }
    final_gemm<<<NN / 16, 64, 0, stream>>>(xin, Wo, bo, out);
}

// Round 4
// 471.941 us; speedup vs baseline: 1.7699x; 1.7699x over previous
//
#include <hip/hip_runtime.h>
#include <math.h>

// Problem constants (from reference)
#define NN 20000      // nodes
#define EE 640000     // edges
#define HH 2          // heads
#define DD 64         // dim
#define LL 4          // layers
#define HD 128        // H*D

// ---------------- CSR build ----------------

__global__ void hist_kernel(const int* __restrict__ dst, int* __restrict__ deg) {
    int e = blockIdx.x * 256 + threadIdx.x;
    if (e < EE) atomicAdd(&deg[dst[e]], 1);
}

// single-block exclusive scan, 1024 threads, wave-shuffle based
__global__ void scan_kernel(const int* __restrict__ deg, int* __restrict__ offsets, int n) {
    __shared__ int wsum[16];
    __shared__ int carry;
    int tid = threadIdx.x, wid = tid >> 6, lane = tid & 63;
    if (tid == 0) carry = 0;
    __syncthreads();
    for (int base = 0; base < n; base += 1024) {
        int i = base + tid;
        int v = (i < n) ? deg[i] : 0;
        int x = v;
#pragma unroll
        for (int off = 1; off < 64; off <<= 1) {
            int t = __shfl_up(x, off);
            if (lane >= off) x += t;
        }
        if (lane == 63) wsum[wid] = x;
        __syncthreads();
        if (wid == 0) {
            int wv = (lane < 16) ? wsum[lane] : 0;
#pragma unroll
            for (int off = 1; off < 16; off <<= 1) {
                int t = __shfl_up(wv, off);
                if (lane >= off) wv += t;
            }
            if (lane < 16) wsum[lane] = wv;   // inclusive wave sums
        }
        __syncthreads();
        int prefix = carry + (wid > 0 ? wsum[wid - 1] : 0);
        if (i < n) offsets[i] = prefix + x - v;   // exclusive
        __syncthreads();
        if (tid == 0) carry += wsum[15];
        __syncthreads();
    }
    if (threadIdx.x == 0) offsets[n] = carry;
}

__global__ void scatter_kernel(const int* __restrict__ src, const int* __restrict__ dst,
                               const int* __restrict__ offsets, int* __restrict__ cursor,
                               int* __restrict__ csr_src) {
    int e = blockIdx.x * 256 + threadIdx.x;
    if (e >= EE) return;
    int d = dst[e];
    int pos = offsets[d] + atomicAdd(&cursor[d], 1);
    csr_src[pos] = src[e];
}

// ---------------- per-layer kernels ----------------

// xl = x@Wl + bl ; xr = x@Wr + br  ([N,64] x [64,128])
__global__ void gemm_lr(const float* __restrict__ x,
                        const float* __restrict__ Wl, const float* __restrict__ bl,
                        const float* __restrict__ Wr, const float* __restrict__ br,
                        float* __restrict__ xl, float* __restrict__ xr) {
    __shared__ float xs[16][DD];
    int row0 = blockIdx.x * 16;
    for (int t = threadIdx.x; t < 16 * DD; t += 128) {
        xs[t >> 6][t & 63] = x[row0 * DD + t];
    }
    __syncthreads();
    int j = threadIdx.x;
    float accl[16], accr[16];
    float blv = bl[j], brv = br[j];
#pragma unroll
    for (int r = 0; r < 16; ++r) { accl[r] = blv; accr[r] = brv; }
    for (int k = 0; k < DD; ++k) {
        float wl = Wl[k * HD + j];
        float wr = Wr[k * HD + j];
#pragma unroll
        for (int r = 0; r < 16; ++r) {
            float xv = xs[r][k];
            accl[r] += xv * wl;
            accr[r] += xv * wr;
        }
    }
#pragma unroll
    for (int r = 0; r < 16; ++r) {
        xl[(row0 + r) * HD + j] = accl[r];
        xr[(row0 + r) * HD + j] = accr[r];
    }
}

// Fused GATv2 edge phase: one wave per node.
// Lane layout: group g = lane>>4 (4 groups of 16); head h = g>>1; edge slot es = g&1.
// Each lane holds a float4 feature quarter: features fo = (lane&15)*4 .. +3 of head h.
// Per iteration the wave processes 2 edges x 2 heads with ONE dwordx4 gather instr
// and 6 DS ops total (vs ~30 in the one-edge-per-wave mapping). No LDS, no syncs.
__global__ void fused_aggregate(const float* __restrict__ xl, const float* __restrict__ xr,
                                const float* __restrict__ att, const int* __restrict__ offsets,
                                const int* __restrict__ csr_src, const float* __restrict__ bias,
                                float* __restrict__ xout) {
    int lane = threadIdx.x & 63;
    int node = blockIdx.x * 4 + (threadIdx.x >> 6);
    int g = lane >> 4;
    int h = g >> 1;       // head
    int es = g & 1;       // edge slot within iteration
    int fo = (lane & 15) * 4;

    int start = offsets[node];
    int deg = offsets[node + 1] - start;

    const float4 xrv = *(const float4*)&xr[(long)node * HD + h * 64 + fo];
    const float4 attv = *(const float4*)&att[h * 64 + fo];

    float m = -INFINITY;          // running max  (uniform within head half)
    float ssum = 0.f;             // running denom (uniform within head half)
    float4 acc = {0.f, 0.f, 0.f, 0.f};   // per-slot partial message

    for (int base = 0; base < deg; base += 64) {
        int bcnt = min(64, deg - base);
        int sidx = (lane < bcnt) ? csr_src[start + base + lane] : 0;
        int niter = (bcnt + 1) >> 1;

        int s0 = __shfl(sidx, es);
        float4 xlv = *(const float4*)&xl[(long)s0 * HD + h * 64 + fo];

        for (int i = 0; i < niter; ++i) {
            float4 nxt = {0.f, 0.f, 0.f, 0.f};
            if (i + 1 < niter) {   // wave-uniform; prefetch next iteration's gather
                int s1 = __shfl(sidx, 2 * (i + 1) + es);
                nxt = *(const float4*)&xl[(long)s1 * HD + h * 64 + fo];
            }
            // attention partial: att . leaky_relu(xl + xr, 0.2), this lane's quarter
            float4 v;
            v.x = xlv.x + xrv.x; v.y = xlv.y + xrv.y;
            v.z = xlv.z + xrv.z; v.w = xlv.w + xrv.w;
            v.x = v.x > 0.f ? v.x : 0.2f * v.x;
            v.y = v.y > 0.f ? v.y : 0.2f * v.y;
            v.z = v.z > 0.f ? v.z : 0.2f * v.z;
            v.w = v.w > 0.f ? v.w : 0.2f * v.w;
            float t = fmaf(v.x, attv.x, fmaf(v.y, attv.y, fmaf(v.z, attv.z, v.w * attv.w)));
            // reduce across the 16-lane group
            t += __shfl_xor(t, 1);
            t += __shfl_xor(t, 2);
            t += __shfl_xor(t, 4);
            t += __shfl_xor(t, 8);
            // exchange with the other edge slot of this head
            float tO = __shfl_xor(t, 16);
            bool valid  = (2 * i + es) < bcnt;
            bool validO = (2 * i + (1 - es)) < bcnt;
            float lg  = valid  ? t  : -INFINITY;
            float lgO = validO ? tO : -INFINITY;
            // online softmax update (uniform across the head's 32 lanes)
            float mn = fmaxf(m, fmaxf(lg, lgO));
            float c  = __expf(m - mn);        // exp(-inf)=0 handles first edge
            float w  = __expf(lg - mn);
            float wO = __expf(lgO - mn);
            ssum = fmaf(ssum, c, w + wO);
            acc.x = fmaf(acc.x, c, w * xlv.x);
            acc.y = fmaf(acc.y, c, w * xlv.y);
            acc.z = fmaf(acc.z, c, w * xlv.z);
            acc.w = fmaf(acc.w, c, w * xlv.w);
            m = mn;
            xlv = nxt;
        }
    }

    // combine the two edge-slot partials of each head
    acc.x += __shfl_xor(acc.x, 16);
    acc.y += __shfl_xor(acc.y, 16);
    acc.z += __shfl_xor(acc.z, 16);
    acc.w += __shfl_xor(acc.w, 16);

    float inv = 1.0f / (ssum + 1e-16f);      // per-head denom (deg==0 -> acc=0)
    float4 r;
    r.x = acc.x * inv; r.y = acc.y * inv; r.z = acc.z * inv; r.w = acc.w * inv;

    // combine heads (lane L <-> L+32 hold same features of head 0 / head 1)
    r.x += __shfl_xor(r.x, 32);
    r.y += __shfl_xor(r.y, 32);
    r.z += __shfl_xor(r.z, 32);
    r.w += __shfl_xor(r.w, 32);

    if (lane < 16) {
        const float4 bv = *(const float4*)&bias[fo];
        float4 o;
        o.x = 0.5f * r.x + bv.x;
        o.y = 0.5f * r.y + bv.y;
        o.z = 0.5f * r.z + bv.z;
        o.w = 0.5f * r.w + bv.w;
        o.x = o.x > 0.f ? o.x : 0.01f * o.x;
        o.y = o.y > 0.f ? o.y : 0.01f * o.y;
        o.z = o.z > 0.f ? o.z : 0.01f * o.z;
        o.w = o.w > 0.f ? o.w : 0.01f * o.w;
        *(float4*)&xout[(long)node * DD + fo] = o;
    }
}

// out = leaky_relu(x @ Wo + bo, 0.01); 16 rows/block, 64 threads
__global__ void final_gemm(const float* __restrict__ x, const float* __restrict__ Wo,
                           const float* __restrict__ bo, float* __restrict__ out) {
    __shared__ float xs[16][DD];
    int row0 = blockIdx.x * 16;
    for (int t = threadIdx.x; t < 16 * DD; t += 64) {
        xs[t >> 6][t & 63] = x[row0 * DD + t];
    }
    __syncthreads();
    int j = threadIdx.x;
    float acc[16];
    float bv = bo[j];
#pragma unroll
    for (int r = 0; r < 16; ++r) acc[r] = bv;
    for (int k = 0; k < DD; ++k) {
        float w = Wo[k * DD + j];
#pragma unroll
        for (int r = 0; r < 16; ++r) acc[r] += xs[r][k] * w;
    }
#pragma unroll
    for (int r = 0; r < 16; ++r) {
        float v = acc[r];
        v = v > 0.f ? v : 0.01f * v;
        out[(row0 + r) * DD + j] = v;
    }
}

extern "C" void kernel_launch(void* const* d_in, const int* in_sizes, int n_in,
                              void* d_out, int out_size, void* d_ws, size_t ws_size,
                              hipStream_t stream) {
    const int* edge_index = (const int*)d_in[0];
    const int* src = edge_index;
    const int* dst = edge_index + EE;
    // d_in[1] = edge_weight, unused
    const float* pert = (const float*)d_in[2];
    const float* Wl = (const float*)d_in[3];
    const float* bl = (const float*)d_in[4];
    const float* Wr = (const float*)d_in[5];
    const float* br = (const float*)d_in[6];
    const float* att = (const float*)d_in[7];
    const float* bias = (const float*)d_in[8];
    const float* Wo = (const float*)d_in[9];
    const float* bo = (const float*)d_in[10];
    float* out = (float*)d_out;

    // workspace carve-up
    char* w = (char*)d_ws;
    float* xl = (float*)w;            w += (size_t)NN * HD * 4;
    float* xr = (float*)w;            w += (size_t)NN * HD * 4;
    float* xb0 = (float*)w;           w += (size_t)NN * DD * 4;
    float* xb1 = (float*)w;           w += (size_t)NN * DD * 4;
    int* deg = (int*)w;               w += (size_t)NN * 4;
    int* offsets = (int*)w;           w += (size_t)(NN + 1) * 4 + 4; // keep alignment
    int* cursor = (int*)w;            w += (size_t)NN * 4;
    int* csr_src = (int*)w;           w += (size_t)EE * 4;

    // CSR build (dst is layer-invariant; built once per launch)
    hipMemsetAsync(deg, 0, (size_t)NN * 4, stream);
    hipMemsetAsync(cursor, 0, (size_t)NN * 4, stream);
    hist_kernel<<<(EE + 255) / 256, 256, 0, stream>>>(dst, deg);
    scan_kernel<<<1, 1024, 0, stream>>>(deg, offsets, NN);
    scatter_kernel<<<(EE + 255) / 256, 256, 0, stream>>>(src, dst, offsets, cursor, csr_src);

    const float* xin = pert;
    float* bufs[2] = {xb0, xb1};
    for (int l = 0; l < LL; ++l) {
        gemm_lr<<<NN / 16, 128, 0, stream>>>(xin, Wl + (size_t)l * DD * HD, bl + (size_t)l * HD,
                                             Wr + (size_t)l * DD * HD, br + (size_t)l * HD, xl, xr);
        fused_aggregate<<<NN / 4, 256, 0, stream>>>(xl, xr, att + (size_t)l * HD, offsets,
                                                    csr_src, bias + (size_t)l * DD, bufs[l & 1]);
        xin = bufs[l & 1];
    }
    final_gemm<<<NN / 16, 64, 0, stream>>>(xin, Wo, bo, out);
}